// Round 1
// 113.137 us; speedup vs baseline: 1.3083x; 1.3083x over previous
//
#include <hip/hip_runtime.h>

#define NROWS 4096
#define DDIM  256
#define MARGIN 0.1f
#define GX 32
#define GY 32
#define NBLOCKS (GX * GY)

typedef __attribute__((ext_vector_type(8)))  _Float16 half8;
typedef __attribute__((ext_vector_type(16))) float    floatx16;

// ---------------- Kernel A: diag + zero rank ----------------
__global__ __launch_bounds__(256) void diag_kernel(
    const float* __restrict__ v, const float* __restrict__ t,
    float* __restrict__ diag, int* __restrict__ rank) {
  const int wv   = threadIdx.x >> 6;
  const int lane = threadIdx.x & 63;
  const int row  = blockIdx.x * 4 + wv;
  const float4 a = ((const float4*)(v + (size_t)row * DDIM))[lane];
  const float4 b = ((const float4*)(t + (size_t)row * DDIM))[lane];
  float s = a.x*b.x + a.y*b.y + a.z*b.z + a.w*b.w;
  #pragma unroll
  for (int off = 32; off; off >>= 1) s += __shfl_down(s, off);
  if (lane == 0) { diag[row] = s; rank[row] = 0; }
}

// async global->LDS, 16B per lane, linear LDS dest (wave base + lane*16)
#define GLOAD16(gp, lp) \
  __builtin_amdgcn_global_load_lds( \
      (const __attribute__((address_space(1))) unsigned int*)(gp), \
      (__attribute__((address_space(3))) unsigned int*)(lp), 16, 0, 0)

// fp32x8 -> (hi, lo) fp16 split, RNE both (identical numerics to prior kernel)
__device__ inline void cvt8(const float4 x0, const float4 x1,
                            half8& h, half8& l) {
  h[0] = (_Float16)x0.x; l[0] = (_Float16)(x0.x - (float)h[0]);
  h[1] = (_Float16)x0.y; l[1] = (_Float16)(x0.y - (float)h[1]);
  h[2] = (_Float16)x0.z; l[2] = (_Float16)(x0.z - (float)h[2]);
  h[3] = (_Float16)x0.w; l[3] = (_Float16)(x0.w - (float)h[3]);
  h[4] = (_Float16)x1.x; l[4] = (_Float16)(x1.x - (float)h[4]);
  h[5] = (_Float16)x1.y; l[5] = (_Float16)(x1.y - (float)h[5]);
  h[6] = (_Float16)x1.z; l[6] = (_Float16)(x1.z - (float)h[6]);
  h[7] = (_Float16)x1.w; l[7] = (_Float16)(x1.w - (float)h[7]);
}

// ---------------- Kernel B: fused MFMA GEMM + epilogue ----------------
// 128x128 block tile, 4 waves of 64x64, BK=32, fp32 staged via global_load_lds
// (linear dest + XOR-swizzled source), hi/lo fp16 split at fragment-read time.
// Swizzle: physical_byte = logical_byte ^ ((row & 7) << 4)  (involution, T2).
__global__ __launch_bounds__(256, 4) void main_kernel(
    const float* __restrict__ v, const float* __restrict__ t,
    const float* __restrict__ diag, float* __restrict__ pvt,
    float* __restrict__ ptv, int* __restrict__ rank) {
  __shared__ __align__(16) float Af[128 * 32];
  __shared__ __align__(16) float Bf[128 * 32];
  __shared__ float sdi[128];
  __shared__ float sdj[128];
  __shared__ float red[8];

  const int tid  = threadIdx.x;
  const int w    = tid >> 6;
  const int lane = tid & 63;
  const int i0   = blockIdx.y * 128;
  const int j0   = blockIdx.x * 128;

  if (tid < 128) sdi[tid] = diag[i0 + tid];
  else           sdj[tid - 128] = diag[j0 + tid - 128];

  // staging: wave w stages rows [w*32, w*32+32) of A and B; instr p covers 8 rows.
  // lane l -> row = w*32 + p*8 + (l>>3); LDS dest is linear (row*128 + (l&7)*16),
  // so the SOURCE column is pre-swizzled: src_byte = ((l&7)*16) ^ ((row&7)<<4).
  const int rsub = lane >> 3;                           // row&7 (p*8, w*32 keep low bits)
  const int cswz = ((lane & 7) * 16) ^ (rsub << 4);     // swizzled source byte col
  const float* aSrc = v + (size_t)(i0 + w * 32 + rsub) * DDIM + (cswz >> 2);
  const float* bSrc = t + (size_t)(j0 + w * 32 + rsub) * DDIM + (cswz >> 2);
  char* aDst = (char*)Af + w * 4096;
  char* bDst = (char*)Bf + w * 4096;

  floatx16 acc[2][2];
  #pragma unroll
  for (int mt = 0; mt < 2; ++mt)
    #pragma unroll
    for (int nt = 0; nt < 2; ++nt)
      #pragma unroll
      for (int r = 0; r < 16; ++r) acc[mt][nt][r] = 0.f;

  const int mrow  = lane & 31;
  const int hsel  = lane >> 5;
  const int arow0 = (w >> 1) * 64 + mrow;
  const int brow0 = (w & 1) * 64 + mrow;
  const int asw   = (arow0 & 7) << 4;   // mt*32 doesn't change row&7
  const int bsw   = (brow0 & 7) << 4;

  for (int s = 0; s < 8; ++s) {
    __syncthreads();                    // previous compute done reading LDS
    #pragma unroll
    for (int p = 0; p < 4; ++p)
      GLOAD16(aSrc + (size_t)(p * 8) * DDIM + s * 32, aDst + p * 1024);
    #pragma unroll
    for (int p = 0; p < 4; ++p)
      GLOAD16(bSrc + (size_t)(p * 8) * DDIM + s * 32, bDst + p * 1024);
    __syncthreads();                    // compiler drains vmcnt(0) before barrier

    #pragma unroll
    for (int ks = 0; ks < 2; ++ks) {
      const int cb = ks * 64 + hsel * 32;   // logical byte col of 8-elem K group
      half8 bh[2], bl[2];
      #pragma unroll
      for (int nt = 0; nt < 2; ++nt) {
        const char* bq = (const char*)Bf + (brow0 + nt * 32) * 128;
        const int  pc = cb ^ bsw;
        cvt8(*(const float4*)(bq + pc), *(const float4*)(bq + (pc ^ 16)),
             bh[nt], bl[nt]);
      }
      #pragma unroll
      for (int mt = 0; mt < 2; ++mt) {
        const char* aq = (const char*)Af + (arow0 + mt * 32) * 128;
        const int  pa = cb ^ asw;
        half8 ah, al;
        cvt8(*(const float4*)(aq + pa), *(const float4*)(aq + (pa ^ 16)), ah, al);
        #pragma unroll
        for (int nt = 0; nt < 2; ++nt) {
          acc[mt][nt] = __builtin_amdgcn_mfma_f32_32x32x16_f16(al, bh[nt], acc[mt][nt], 0, 0, 0);
          acc[mt][nt] = __builtin_amdgcn_mfma_f32_32x32x16_f16(ah, bl[nt], acc[mt][nt], 0, 0, 0);
          acc[mt][nt] = __builtin_amdgcn_mfma_f32_32x32x16_f16(ah, bh[nt], acc[mt][nt], 0, 0, 0);
        }
      }
    }
  }

  // ---- epilogue: C/D layout col=lane&31, row=(reg&3)+8*(reg>>2)+4*(lane>>5) ----
  float vt = 0.f, tv = 0.f;
  const int colL = lane & 31;
  #pragma unroll
  for (int mt = 0; mt < 2; ++mt) {
    const int rbase = (w >> 1) * 64 + mt * 32;
    #pragma unroll
    for (int reg = 0; reg < 16; ++reg) {
      const int r  = (reg & 3) + 8 * (reg >> 2) + 4 * hsel;
      const int gi = i0 + rbase + r;
      const float di = sdi[rbase + r];
      unsigned long long b0 = 0, b1 = 0;
      #pragma unroll
      for (int nt = 0; nt < 2; ++nt) {
        const int c  = (w & 1) * 64 + nt * 32 + colL;
        const int gj = j0 + c;
        const float sc = acc[mt][nt][reg];
        const float dj = sdj[c];
        const bool ne = (gi != gj);
        if (ne) {
          vt += fmaxf(0.f, MARGIN - di + sc);
          tv += fmaxf(0.f, MARGIN - dj + sc);
        }
        const unsigned long long bb = __ballot(ne && (sc > di));
        if (nt == 0) b0 = bb; else b1 = bb;
      }
      if (colL == 0) {
        const int c = hsel ? (int)(__popcll(b0 >> 32) + __popcll(b1 >> 32))
                           : (int)(__popcll(b0 & 0xFFFFFFFFull) + __popcll(b1 & 0xFFFFFFFFull));
        atomicAdd(&rank[gi], c);
      }
    }
  }
  #pragma unroll
  for (int off = 32; off; off >>= 1) {
    vt += __shfl_down(vt, off);
    tv += __shfl_down(tv, off);
  }
  if (lane == 0) { red[w] = vt; red[4 + w] = tv; }
  __syncthreads();
  if (tid == 0) {
    const int bid = blockIdx.y * GX + blockIdx.x;
    pvt[bid] = red[0] + red[1] + red[2] + red[3];
    ptv[bid] = red[4] + red[5] + red[6] + red[7];
  }
}

// ---------------- Kernel C: final reduction -> 6 outputs ----------------
__global__ __launch_bounds__(256) void final_kernel(
    const float* __restrict__ pvt, const float* __restrict__ ptv,
    const int* __restrict__ rank, float* __restrict__ out) {
  __shared__ int s1[4], s5[4], s10[4], ssum[4];
  __shared__ float sv[4], st[4];
  const int tid = threadIdx.x;
  int c1 = 0, c5 = 0, c10 = 0, cs = 0;
  for (int i = tid; i < NROWS; i += 256) {
    const int r = rank[i];
    c1  += (r < 1);
    c5  += (r < 5);
    c10 += (r < 10);
    cs  += r;
  }
  float fv = 0.f, ft = 0.f;
  for (int i = tid; i < NBLOCKS; i += 256) { fv += pvt[i]; ft += ptv[i]; }
  #pragma unroll
  for (int off = 32; off; off >>= 1) {
    c1  += __shfl_down(c1, off);
    c5  += __shfl_down(c5, off);
    c10 += __shfl_down(c10, off);
    cs  += __shfl_down(cs, off);
    fv  += __shfl_down(fv, off);
    ft  += __shfl_down(ft, off);
  }
  const int w = tid >> 6;
  if ((tid & 63) == 0) { s1[w] = c1; s5[w] = c5; s10[w] = c10; ssum[w] = cs; sv[w] = fv; st[w] = ft; }
  __syncthreads();
  if (tid == 0) {
    int a1 = 0, a5 = 0, a10 = 0, as = 0; float av = 0.f, at = 0.f;
    for (int k = 0; k < 4; ++k) {
      a1 += s1[k]; a5 += s5[k]; a10 += s10[k]; as += ssum[k];
      av += sv[k]; at += st[k];
    }
    const float denom = 4096.0f * 4095.0f;
    out[0] = av / denom;
    out[1] = at / denom;
    out[2] = a1  / 4096.0f;
    out[3] = a5  / 4096.0f;
    out[4] = a10 / 4096.0f;
    out[5] = (float)as / 4096.0f;
  }
}

extern "C" void kernel_launch(void* const* d_in, const int* in_sizes, int n_in,
                              void* d_out, int out_size, void* d_ws, size_t ws_size,
                              hipStream_t stream) {
  const float* v = (const float*)d_in[0];
  const float* t = (const float*)d_in[1];
  float* out = (float*)d_out;

  float* diag = (float*)d_ws;
  int*   rank = (int*)((char*)d_ws + NROWS * sizeof(float));
  float* pvt  = (float*)((char*)d_ws + 2 * (size_t)NROWS * sizeof(float));
  float* ptv  = pvt + NBLOCKS;

  hipLaunchKernelGGL(diag_kernel, dim3(NROWS / 4), dim3(256), 0, stream,
                     v, t, diag, rank);
  hipLaunchKernelGGL(main_kernel, dim3(GX, GY), dim3(256), 0, stream,
                     v, t, diag, pvt, ptv, rank);
  hipLaunchKernelGGL(final_kernel, dim3(1), dim3(256), 0, stream, pvt, ptv, rank, out);
}